// Round 1
// baseline (476.668 us; speedup 1.0000x reference)
//
#include <hip/hip_runtime.h>
#include <math.h>

// Sparsemax over rows of a (ROWS x 4096) float32 matrix.
// Method: Michelot's simplex-projection algorithm (exact, sort-free).
//   S_0 = all elements (after subtracting row max, matching the reference)
//   tau_k = (sum(S_k) - 1) / |S_k|
//   S_{k+1} = { i in S_k : x_i > tau_k }
//   stop when |S| stops changing; out_i = max(x_i - tau, 0)
// Converges to the exact sparsemax tau; elements equal to tau contribute 0
// either way, so tie handling does not affect the output.

constexpr int N_COLS = 4096;
constexpr int BLOCK = 256;
constexpr int PER_THREAD = N_COLS / BLOCK; // 16 floats/thread, register-resident
constexpr int WAVES = BLOCK / 64;          // 4 waves/block

__global__ __launch_bounds__(BLOCK) void sparsemax_kernel(
    const float* __restrict__ x, float* __restrict__ out) {
  const int row = blockIdx.x;
  const float* xr = x + (size_t)row * N_COLS;
  float* outr = out + (size_t)row * N_COLS;
  const int t = threadIdx.x;
  const int wave = t >> 6;
  const int lane = t & 63;

  // ---- load row into registers, coalesced float4 ----
  float v[PER_THREAD];
  const float4* x4 = (const float4*)xr;
#pragma unroll
  for (int k = 0; k < PER_THREAD / 4; ++k) {
    float4 f = x4[t + k * BLOCK];
    v[4 * k + 0] = f.x;
    v[4 * k + 1] = f.y;
    v[4 * k + 2] = f.z;
    v[4 * k + 3] = f.w;
  }

  __shared__ float s_sum[WAVES];
  __shared__ float s_cnt[WAVES];
  __shared__ float s_bcast[2];

  // ---- row max (numerical stabilization, matches reference) ----
  float m = -INFINITY;
#pragma unroll
  for (int k = 0; k < PER_THREAD; ++k) m = fmaxf(m, v[k]);
#pragma unroll
  for (int off = 32; off >= 1; off >>= 1) m = fmaxf(m, __shfl_down(m, off, 64));
  if (lane == 0) s_sum[wave] = m;
  __syncthreads();
  if (t == 0) {
    float mm = s_sum[0];
    for (int w = 1; w < WAVES; ++w) mm = fmaxf(mm, s_sum[w]);
    s_bcast[0] = mm;
  }
  __syncthreads();
  m = s_bcast[0];
#pragma unroll
  for (int k = 0; k < PER_THREAD; ++k) v[k] -= m;
  __syncthreads();  // everyone done reading s_bcast[0] before loop reuses it

  // ---- Michelot iterations ----
  unsigned act = (1u << PER_THREAD) - 1;  // per-thread active-element bitmask
  float tau = 0.0f;
  int prev_cnt = -1;
  for (int it = 0; it < 64; ++it) {
    float s = 0.0f, c = 0.0f;
#pragma unroll
    for (int k = 0; k < PER_THREAD; ++k) {
      if ((act >> k) & 1u) {
        s += v[k];
        c += 1.0f;
      }
    }
#pragma unroll
    for (int off = 32; off >= 1; off >>= 1) {
      s += __shfl_down(s, off, 64);
      c += __shfl_down(c, off, 64);
    }
    if (lane == 0) {
      s_sum[wave] = s;
      s_cnt[wave] = c;
    }
    __syncthreads();
    if (t == 0) {
      float ss = 0.0f, cc = 0.0f;
      for (int w = 0; w < WAVES; ++w) {
        ss += s_sum[w];
        cc += s_cnt[w];
      }
      s_bcast[0] = (ss - 1.0f) / cc;
      s_bcast[1] = cc;
    }
    __syncthreads();
    tau = s_bcast[0];
    int cnt = (int)s_bcast[1];
    __syncthreads();  // all read s_bcast before next iteration overwrites
    if (cnt == prev_cnt) break;  // uniform across block
    prev_cnt = cnt;
#pragma unroll
    for (int k = 0; k < PER_THREAD; ++k) {
      if (((act >> k) & 1u) && v[k] <= tau) act &= ~(1u << k);
    }
  }

  // ---- write out = max(x - tau, 0), coalesced float4 ----
  float4* o4 = (float4*)outr;
#pragma unroll
  for (int k = 0; k < PER_THREAD / 4; ++k) {
    float4 f;
    f.x = fmaxf(v[4 * k + 0] - tau, 0.0f);
    f.y = fmaxf(v[4 * k + 1] - tau, 0.0f);
    f.z = fmaxf(v[4 * k + 2] - tau, 0.0f);
    f.w = fmaxf(v[4 * k + 3] - tau, 0.0f);
    o4[t + k * BLOCK] = f;
  }
}

extern "C" void kernel_launch(void* const* d_in, const int* in_sizes, int n_in,
                              void* d_out, int out_size, void* d_ws,
                              size_t ws_size, hipStream_t stream) {
  const float* x = (const float*)d_in[0];
  float* out = (float*)d_out;
  const int rows = in_sizes[0] / N_COLS;  // 16384
  sparsemax_kernel<<<rows, BLOCK, 0, stream>>>(x, out);
}

// Round 2
// 436.695 us; speedup vs baseline: 1.0915x; 1.0915x over previous
//
#include <hip/hip_runtime.h>
#include <math.h>

// Sparsemax over rows of a (16384 x 4096) float32 matrix.
//
// Key bound: tau >= max(x) - 1  (since z1 - tau <= sum(z_i - tau)_+ = 1).
// => support subset of {x : x > max - 1}. For N(0,1) rows that's ~22 elems.
// Michelot's algorithm started from ANY superset of the support converges to
// the exact sparsemax tau (tau_0 >= -1 since sum(y+1) >= y_max+1 = 1 over the
// candidate set, tau is non-decreasing, so non-candidates y <= -1 stay out).
//
// Structure: block row-max reduction -> LDS candidate gather (atomicAdd) ->
// wave 0 solves tau on <=64 candidates with shuffle butterflies (no barriers)
// -> broadcast -> vectorized write. Block-wide Michelot fallback for the
// (statistically never-hit) case of >64 candidates.

constexpr int N_COLS = 4096;
constexpr int BLOCK = 256;
constexpr int PER_THREAD = N_COLS / BLOCK;  // 16
constexpr int WAVES = BLOCK / 64;           // 4
constexpr int CAP = 64;                     // candidate capacity (1 wave)

__global__ __launch_bounds__(BLOCK) void sparsemax_kernel(
    const float* __restrict__ x, float* __restrict__ out) {
  const int row = blockIdx.x;
  const float4* x4 = (const float4*)(x + (size_t)row * N_COLS);
  float4* o4 = (float4*)(out + (size_t)row * N_COLS);
  const int t = threadIdx.x;
  const int wave = t >> 6;
  const int lane = t & 63;

  // ---- load row into registers, coalesced float4 ----
  float v[PER_THREAD];
#pragma unroll
  for (int k = 0; k < PER_THREAD / 4; ++k) {
    float4 f = x4[t + k * BLOCK];
    v[4 * k + 0] = f.x;
    v[4 * k + 1] = f.y;
    v[4 * k + 2] = f.z;
    v[4 * k + 3] = f.w;
  }

  __shared__ float s_red[WAVES];
  __shared__ float s_cand[CAP];
  __shared__ int s_n;
  __shared__ float s_tau;

  // ---- row max ----
  float m = v[0];
#pragma unroll
  for (int k = 1; k < PER_THREAD; ++k) m = fmaxf(m, v[k]);
#pragma unroll
  for (int off = 32; off >= 1; off >>= 1) m = fmaxf(m, __shfl_xor(m, off, 64));
  if (lane == 0) s_red[wave] = m;
  if (t == 0) s_n = 0;
  __syncthreads();
  m = fmaxf(fmaxf(s_red[0], s_red[1]), fmaxf(s_red[2], s_red[3]));

  // ---- shift and gather candidates y > -1 into LDS ----
#pragma unroll
  for (int k = 0; k < PER_THREAD; ++k) {
    float y = v[k] - m;
    v[k] = y;
    if (y > -1.0f) {
      int idx = atomicAdd(&s_n, 1);
      if (idx < CAP) s_cand[idx] = y;
    }
  }
  __syncthreads();
  const int cnt = s_n;  // uniform across block

  if (cnt <= CAP) {
    // ---- wave 0 solves tau on the candidate set, shuffle-only ----
    if (wave == 0) {
      const bool in = lane < cnt;
      float y = in ? s_cand[lane] : -3.0e38f;
      bool active = in;
      float tau = -1.0f;
      int prev = -1;
      for (int it = 0; it < 32; ++it) {
        float s = active ? y : 0.0f;
        float c = active ? 1.0f : 0.0f;
#pragma unroll
        for (int off = 32; off >= 1; off >>= 1) {
          s += __shfl_xor(s, off, 64);
          c += __shfl_xor(c, off, 64);
        }
        tau = (s - 1.0f) / c;  // uniform across wave
        int ci = (int)c;
        if (ci == prev) break;
        prev = ci;
        active = active && (y > tau);
      }
      if (lane == 0) s_tau = tau;
    }
    __syncthreads();
    const float tau = s_tau;
#pragma unroll
    for (int k = 0; k < PER_THREAD / 4; ++k) {
      float4 f;
      f.x = fmaxf(v[4 * k + 0] - tau, 0.0f);
      f.y = fmaxf(v[4 * k + 1] - tau, 0.0f);
      f.z = fmaxf(v[4 * k + 2] - tau, 0.0f);
      f.w = fmaxf(v[4 * k + 3] - tau, 0.0f);
      o4[t + k * BLOCK] = f;
    }
  } else {
    // ---- fallback: block-wide Michelot on the full (shifted) row ----
    __shared__ float s_sum[WAVES];
    __shared__ float s_cnt[WAVES];
    __shared__ float s_b[2];
    unsigned act = (1u << PER_THREAD) - 1;
    float tau = 0.0f;
    int prev_cnt = -1;
    for (int it = 0; it < 64; ++it) {
      float s = 0.0f, c = 0.0f;
#pragma unroll
      for (int k = 0; k < PER_THREAD; ++k) {
        if ((act >> k) & 1u) {
          s += v[k];
          c += 1.0f;
        }
      }
#pragma unroll
      for (int off = 32; off >= 1; off >>= 1) {
        s += __shfl_down(s, off, 64);
        c += __shfl_down(c, off, 64);
      }
      if (lane == 0) {
        s_sum[wave] = s;
        s_cnt[wave] = c;
      }
      __syncthreads();
      if (t == 0) {
        float ss = 0.0f, cc = 0.0f;
        for (int w = 0; w < WAVES; ++w) {
          ss += s_sum[w];
          cc += s_cnt[w];
        }
        s_b[0] = (ss - 1.0f) / cc;
        s_b[1] = cc;
      }
      __syncthreads();
      tau = s_b[0];
      int c_now = (int)s_b[1];
      __syncthreads();
      if (c_now == prev_cnt) break;
      prev_cnt = c_now;
#pragma unroll
      for (int k = 0; k < PER_THREAD; ++k) {
        if (((act >> k) & 1u) && v[k] <= tau) act &= ~(1u << k);
      }
    }
#pragma unroll
    for (int k = 0; k < PER_THREAD / 4; ++k) {
      float4 f;
      f.x = fmaxf(v[4 * k + 0] - tau, 0.0f);
      f.y = fmaxf(v[4 * k + 1] - tau, 0.0f);
      f.z = fmaxf(v[4 * k + 2] - tau, 0.0f);
      f.w = fmaxf(v[4 * k + 3] - tau, 0.0f);
      o4[t + k * BLOCK] = f;
    }
  }
}

extern "C" void kernel_launch(void* const* d_in, const int* in_sizes, int n_in,
                              void* d_out, int out_size, void* d_ws,
                              size_t ws_size, hipStream_t stream) {
  const float* x = (const float*)d_in[0];
  float* out = (float*)d_out;
  const int rows = in_sizes[0] / N_COLS;  // 16384
  sparsemax_kernel<<<rows, BLOCK, 0, stream>>>(x, out);
}

// Round 3
// 435.586 us; speedup vs baseline: 1.0943x; 1.0025x over previous
//
#include <hip/hip_runtime.h>
#include <math.h>

// Sparsemax over rows of a (16384 x 4096) float32 matrix.
//
// Bound: tau >= max(x) - 1  (z1 - tau <= sum(z_i - tau)_+ = 1), so the
// support lies in {x : x > max - 1} (~22 elems for N(0,1) rows of 4096).
// Candidates are gathered to LDS; then EVERY wave redundantly solves tau
// exactly in one pass via the rank formula: for candidate y_i,
//   C_i = #{j : y_j >= y_i},  S_i = sum{y_j : y_j >= y_i}
//   support size k = max C_i over lanes with 1 + C_i*y_i > S_i
//   tau = (S_i - 1)/C_i at that lane      (identical to the reference's
//   sorted cumsum formula for distinct values; ties are measure-zero)
// No iteration, no dependent shuffle chains, 2 barriers total.

constexpr int N_COLS = 4096;
constexpr int BLOCK = 256;
constexpr int PER_THREAD = N_COLS / BLOCK;  // 16
constexpr int WAVES = BLOCK / 64;           // 4
constexpr int CAP = 64;                     // candidate capacity (1 wave)

__global__ __launch_bounds__(BLOCK) void sparsemax_kernel(
    const float* __restrict__ x, float* __restrict__ out) {
  const int row = blockIdx.x;
  const float4* x4 = (const float4*)(x + (size_t)row * N_COLS);
  float4* o4 = (float4*)(out + (size_t)row * N_COLS);
  const int t = threadIdx.x;
  const int wave = t >> 6;
  const int lane = t & 63;

  // ---- load row into registers, coalesced float4 (kept as raw x) ----
  float v[PER_THREAD];
#pragma unroll
  for (int k = 0; k < PER_THREAD / 4; ++k) {
    float4 f = x4[t + k * BLOCK];
    v[4 * k + 0] = f.x;
    v[4 * k + 1] = f.y;
    v[4 * k + 2] = f.z;
    v[4 * k + 3] = f.w;
  }

  __shared__ float s_red[WAVES];
  __shared__ float s_cand[CAP];
  __shared__ int s_n;

  // ---- row max ----
  float m = v[0];
#pragma unroll
  for (int k = 1; k < PER_THREAD; ++k) m = fmaxf(m, v[k]);
#pragma unroll
  for (int off = 32; off >= 1; off >>= 1) m = fmaxf(m, __shfl_xor(m, off, 64));
  if (lane == 0) s_red[wave] = m;
  if (t == 0) s_n = 0;
  __syncthreads();  // barrier 1
  m = fmaxf(fmaxf(s_red[0], s_red[1]), fmaxf(s_red[2], s_red[3]));

  // ---- gather candidates x > m-1 into LDS (stored shifted: y = x - m) ----
  const float thresh = m - 1.0f;
#pragma unroll
  for (int k = 0; k < PER_THREAD; ++k) {
    if (v[k] > thresh) {
      int idx = atomicAdd(&s_n, 1);
      if (idx < CAP) s_cand[idx] = v[k] - m;
    }
  }
  __syncthreads();  // barrier 2
  const int cnt = s_n;  // uniform across block

  float tau;  // in shifted space
  if (cnt <= CAP) {
    // ---- every wave solves redundantly: exact one-pass rank formula ----
    const bool in = lane < cnt;
    float y = in ? s_cand[lane] : 1.0f;  // sentinel never read via shfl(j<cnt)
    float S = 0.0f, C = 0.0f;
    for (int j = 0; j < cnt; ++j) {  // uniform trip count; shfl j is uniform
      float yj = __shfl(y, j, 64);   // lowers to readlane broadcast
      if (yj >= y) {
        S += yj;
        C += 1.0f;
      }
    }
    bool ok = in && (1.0f + C * y > S);
    float bc = ok ? C : 0.0f;
    float bt = ok ? (S - 1.0f) / C : 0.0f;
#pragma unroll
    for (int off = 32; off >= 1; off >>= 1) {
      float oc = __shfl_xor(bc, off, 64);
      float ot = __shfl_xor(bt, off, 64);
      if (oc > bc) {
        bc = oc;
        bt = ot;
      }
    }
    tau = bt;  // uniform across wave (k=max C is unique for distinct values)
  } else {
    // ---- fallback (statistically never): block-wide Michelot ----
    __shared__ float s_sum[WAVES];
    __shared__ float s_cnt[WAVES];
    __shared__ float s_b[2];
    unsigned act = (1u << PER_THREAD) - 1;
    float tb = 0.0f;
    int prev_cnt = -1;
    for (int it = 0; it < 64; ++it) {
      float s = 0.0f, c = 0.0f;
#pragma unroll
      for (int k = 0; k < PER_THREAD; ++k) {
        if ((act >> k) & 1u) {
          s += v[k] - m;
          c += 1.0f;
        }
      }
#pragma unroll
      for (int off = 32; off >= 1; off >>= 1) {
        s += __shfl_down(s, off, 64);
        c += __shfl_down(c, off, 64);
      }
      if (lane == 0) {
        s_sum[wave] = s;
        s_cnt[wave] = c;
      }
      __syncthreads();
      if (t == 0) {
        float ss = 0.0f, cc = 0.0f;
        for (int w = 0; w < WAVES; ++w) {
          ss += s_sum[w];
          cc += s_cnt[w];
        }
        s_b[0] = (ss - 1.0f) / cc;
        s_b[1] = cc;
      }
      __syncthreads();
      tb = s_b[0];
      int c_now = (int)s_b[1];
      __syncthreads();
      if (c_now == prev_cnt) break;
      prev_cnt = c_now;
#pragma unroll
      for (int k = 0; k < PER_THREAD; ++k) {
        if (((act >> k) & 1u) && (v[k] - m) <= tb) act &= ~(1u << k);
      }
    }
    tau = tb;
  }

  // ---- write out = max(x - (m + tau), 0), coalesced float4 ----
  const float T = m + tau;
#pragma unroll
  for (int k = 0; k < PER_THREAD / 4; ++k) {
    float4 f;
    f.x = fmaxf(v[4 * k + 0] - T, 0.0f);
    f.y = fmaxf(v[4 * k + 1] - T, 0.0f);
    f.z = fmaxf(v[4 * k + 2] - T, 0.0f);
    f.w = fmaxf(v[4 * k + 3] - T, 0.0f);
    o4[t + k * BLOCK] = f;
  }
}

extern "C" void kernel_launch(void* const* d_in, const int* in_sizes, int n_in,
                              void* d_out, int out_size, void* d_ws,
                              size_t ws_size, hipStream_t stream) {
  const float* x = (const float*)d_in[0];
  float* out = (float*)d_out;
  const int rows = in_sizes[0] / N_COLS;  // 16384
  sparsemax_kernel<<<rows, BLOCK, 0, stream>>>(x, out);
}